// Round 4
// baseline (140.402 us; speedup 1.0000x reference)
//
#include <hip/hip_runtime.h>
#include <float.h>
#include <math.h>

#define NT 256
#define NW (NT / 64)
#define S 16
#define NB 2048
#define CAP1 1024
#define CAP2 1024
#define QCAP 512
#define TGT 128
#define XMIN (-8.0f)
#define BINW (1.0f / 128.0f)
#define INVW (128.0f)
#define SEPS 1e-5f

__device__ __forceinline__ int binOf(float x) {
  int bn = (int)floorf((x - XMIN) * INVW);
  return bn < 0 ? 0 : (bn > NB - 1 ? NB - 1 : bn);
}
__device__ __forceinline__ unsigned f2k(float f) {
  unsigned u = __float_as_uint(f);
  return (u & 0x80000000u) ? ~u : (u | 0x80000000u);
}
__device__ __forceinline__ float k2f(unsigned k) {
  return __uint_as_float((k & 0x80000000u) ? (k ^ 0x80000000u) : ~k);
}

// -------- K1: single pass: max/argmax + count hist (per-slice, no atomics) -
__global__ __launch_bounds__(NT) void k1(const float* __restrict__ logits,
    int V, int CS, int* __restrict__ hist, float* __restrict__ sMax,
    int* __restrict__ sArg)
{
  const int s = blockIdx.x, b = blockIdx.y, tid = threadIdx.x;
  const float* lrow = logits + (size_t)b * V;
  const int lo = s * CS, hi = min(V, lo + CS);
  __shared__ int lc[NB];
  __shared__ float wv[NW]; __shared__ int wi[NW];
  for (int j = tid; j < NB; j += NT) lc[j] = 0;
  __syncthreads();

  float bm = -FLT_MAX; int bi = 0x7fffffff;
  const int vecEnd = lo + ((hi - lo) & ~3);
  const float4* l4 = reinterpret_cast<const float4*>(lrow);
  #pragma unroll 4
  for (int i4 = (lo >> 2) + tid; i4 < (vecEnd >> 2); i4 += NT) {
    float4 x = l4[i4];
    int base = i4 << 2;
    if (x.x > bm) { bm = x.x; bi = base; }
    if (x.y > bm) { bm = x.y; bi = base + 1; }
    if (x.z > bm) { bm = x.z; bi = base + 2; }
    if (x.w > bm) { bm = x.w; bi = base + 3; }
    atomicAdd(&lc[binOf(x.x)], 1);
    atomicAdd(&lc[binOf(x.y)], 1);
    atomicAdd(&lc[binOf(x.z)], 1);
    atomicAdd(&lc[binOf(x.w)], 1);
  }
  for (int i = vecEnd + tid; i < hi; i += NT) {
    float x = lrow[i];
    if (x > bm) { bm = x; bi = i; }
    atomicAdd(&lc[binOf(x)], 1);
  }
  for (int off = 32; off; off >>= 1) {
    float ov = __shfl_down(bm, off);
    int   oi = __shfl_down(bi, off);
    if (ov > bm || (ov == bm && oi < bi)) { bm = ov; bi = oi; }
  }
  if ((tid & 63) == 0) { wv[tid >> 6] = bm; wi[tid >> 6] = bi; }
  __syncthreads();     // fences lc atomics too
  if (tid == 0) {
    for (int w = 1; w < NW; w++)
      if (wv[w] > bm || (wv[w] == bm && wi[w] < bi)) { bm = wv[w]; bi = wi[w]; }
    sMax[b * S + s] = bm; sArg[b * S + s] = bi;
  }
  int* hslice = hist + ((size_t)b * S + s) * NB;
  for (int j = tid; j < NB; j += NT) hslice[j] = lc[j];
}

// ---- K2: sum slice hists; M/gidx; logZ from hist; edge; mode; zero cnts ---
__global__ __launch_bounds__(NT) void k2(const float* __restrict__ temp,
    const float* __restrict__ topp, const int* __restrict__ topk,
    const int* __restrict__ hist, const float* __restrict__ sMax,
    const int* __restrict__ sArg, float* __restrict__ rowF,
    int* __restrict__ rowI, int* __restrict__ cnt1, int* __restrict__ cnt2)
{
  const int b = blockIdx.x, tid = threadIdx.x;
  __shared__ int lc[NB];
  __shared__ int csum[NT];
  __shared__ float esum[NT];
  __shared__ float shM;
  for (int j = tid; j < NB; j += NT) {
    int tot = 0;
    for (int s2 = 0; s2 < S; s2++) tot += hist[((size_t)b * S + s2) * NB + j];
    lc[j] = tot;
  }
  __syncthreads();
  if (tid == 0) {
    float M = -FLT_MAX; int gi = 0x7fffffff;
    for (int s2 = 0; s2 < S; s2++) {
      float v = sMax[b * S + s2]; int ii = sArg[b * S + s2];
      if (v > M || (v == M && ii < gi)) { M = v; gi = ii; }
    }
    shM = M;
    rowI[b * 16 + 0] = gi;
  }
  __syncthreads();
  const float M = shM;
  const int CH = NB / NT;
  int c0 = 0; float e0 = 0.0f;
  for (int j = tid * CH; j < (tid + 1) * CH; j++) {
    c0 += lc[j];
    if (lc[j]) e0 += (float)lc[j] * __expf(XMIN + (j + 0.5f) * BINW - M);
  }
  csum[tid] = c0; esum[tid] = e0;
  __syncthreads();
  if (tid == 0) {
    float Z = 0.0f;
    for (int c = 0; c < NT; c++) Z += esum[c];
    float logZ = logf(Z);
    int cum = 0; int c = NT - 1;
    for (; c >= 0; c--) {
      if (cum + csum[c] >= TGT) break;
      cum += csum[c];
    }
    if (c < 0) c = 0;
    int bsel = 0, found = -1;
    for (int j = c * CH + CH - 1; j >= c * CH; j--) {
      cum += lc[j];
      if (cum >= TGT) { found = j; break; }
    }
    bsel = (found >= 0) ? found : 0;
    int bc = (bsel >= 2) ? (bsel - 2) : 0;   // 2-bin margin for rank exactness
    float t = temp[b]; float p = topp[b]; int k = topk[b];
    int mode = (t < SEPS) ? 0 : ((k >= 1) ? 1 : 2);
    rowF[b * 16 + 0] = M;
    rowF[b * 16 + 1] = logZ;
    rowF[b * 16 + 2] = XMIN + bc * BINW;     // collect threshold edgeC
    rowF[b * 16 + 3] = (t >= SEPS) ? (M / t) : 0.0f;
    rowF[b * 16 + 4] = t;
    rowF[b * 16 + 5] = p;
    rowI[b * 16 + 1] = mode;
    rowI[b * 16 + 2] = k;
    cnt1[b] = 0; cnt2[b] = 0;
  }
}

// -------- K3: collect candidates >= edgeC (LDS-staged); mass hist mode2 ----
__global__ __launch_bounds__(NT) void k3(const float* __restrict__ logits,
    int V, int CS, const float* __restrict__ rowF, const int* __restrict__ rowI,
    float* __restrict__ mass, float* __restrict__ candV, int* __restrict__ candI,
    int* __restrict__ cnt1)
{
  const int s = blockIdx.x, b = blockIdx.y, tid = threadIdx.x;
  const float edgeC = rowF[b * 16 + 2];
  const float Ms = rowF[b * 16 + 3];
  const float t = rowF[b * 16 + 4];
  const int mode = rowI[b * 16 + 1];
  const float* lrow = logits + (size_t)b * V;
  const int lo = s * CS, hi = min(V, lo + CS);
  __shared__ int qn; __shared__ int sbase;
  __shared__ float qv[QCAP]; __shared__ int qi[QCAP];
  __shared__ float lm[NB];
  if (tid == 0) qn = 0;
  __syncthreads();
  const int vecEnd = lo + ((hi - lo) & ~3);
  const float4* l4 = reinterpret_cast<const float4*>(lrow);
  #pragma unroll 4
  for (int i4 = (lo >> 2) + tid; i4 < (vecEnd >> 2); i4 += NT) {
    float4 xv = l4[i4];
    float xs[4] = {xv.x, xv.y, xv.z, xv.w};
    int base = i4 << 2;
    #pragma unroll
    for (int q = 0; q < 4; q++) {
      float x = xs[q];
      if (x >= edgeC) {
        int ppos = atomicAdd(&qn, 1);
        if (ppos < QCAP) { qv[ppos] = x; qi[ppos] = base + q; }
      }
    }
  }
  for (int i = vecEnd + tid; i < hi; i += NT) {
    float x = lrow[i];
    if (x >= edgeC) {
      int ppos = atomicAdd(&qn, 1);
      if (ppos < QCAP) { qv[ppos] = x; qi[ppos] = i; }
    }
  }
  __syncthreads();
  int qc = min(qn, QCAP);
  if (tid == 0) sbase = atomicAdd(&cnt1[b], qc);
  __syncthreads();
  for (int j = tid; j < qc; j += NT) {
    int dst = sbase + j;
    if (dst < CAP1) { candV[b * CAP1 + dst] = qv[j]; candI[b * CAP1 + dst] = qi[j]; }
  }
  if (mode == 2) {
    for (int j = tid; j < NB; j += NT) lm[j] = 0.0f;
    __syncthreads();
    #pragma unroll 2
    for (int i4 = (lo >> 2) + tid; i4 < (vecEnd >> 2); i4 += NT) {
      float4 xv = l4[i4];
      atomicAdd(&lm[binOf(xv.x)], expf(xv.x / t - Ms));
      atomicAdd(&lm[binOf(xv.y)], expf(xv.y / t - Ms));
      atomicAdd(&lm[binOf(xv.z)], expf(xv.z / t - Ms));
      atomicAdd(&lm[binOf(xv.w)], expf(xv.w / t - Ms));
    }
    for (int i = vecEnd + tid; i < hi; i += NT)
      atomicAdd(&lm[binOf(lrow[i])], expf(lrow[i] / t - Ms));
    __syncthreads();
    float* mslice = mass + ((size_t)b * S + s) * NB;
    for (int j = tid; j < NB; j += NT) mslice[j] = lm[j];
  }
}

// ---- K4: sort, top-K out, modes 0/1 sample+rank+final, mode2 mass scan ----
__global__ __launch_bounds__(NT) void k4(const float* __restrict__ logits,
    const float* __restrict__ noise, int V, int K,
    const float* __restrict__ candV, const int* __restrict__ candI,
    const int* __restrict__ cnt1, const float* __restrict__ mass,
    float* __restrict__ rowF, int* __restrict__ rowI,
    float* __restrict__ out, int Bn)
{
  const int b = blockIdx.x, tid = threadIdx.x;
  __shared__ float cv[CAP1]; __shared__ int ci[CAP1];
  __shared__ float sv[CAP1]; __shared__ int si[CAP1];
  __shared__ float ev[CAP1];
  __shared__ float lmass[NB];
  __shared__ float fsum[NT];
  __shared__ float wv[NW]; __shared__ int wi[NW];
  __shared__ int shI[2]; __shared__ float shF[2];
  const int n = min(cnt1[b], CAP1);
  const float M = rowF[b * 16 + 0], logZ = rowF[b * 16 + 1], Ms = rowF[b * 16 + 3];
  const float t = rowF[b * 16 + 4], p = rowF[b * 16 + 5];
  const int mode = rowI[b * 16 + 1], k = rowI[b * 16 + 2], gidx = rowI[b * 16 + 0];

  for (int j = tid; j < n; j += NT) { cv[j] = candV[b * CAP1 + j]; ci[j] = candI[b * CAP1 + j]; }
  __syncthreads();
  for (int c = tid; c < n; c += NT) {
    float v = cv[c]; int id = ci[c]; int r = 0;
    for (int j = 0; j < n; j++) {
      float w = cv[j];
      r += (w > v) || (w == v && ci[j] < id);
    }
    sv[r] = v; si[r] = id;
  }
  __syncthreads();
  float* out_idx = out + Bn;
  float* out_lp  = out + Bn + (size_t)Bn * (K + 1);
  for (int j = tid; j < K && j < n; j += NT) {
    out_idx[(size_t)b * (K + 1) + 1 + j] = (float)si[j];
    out_lp [(size_t)b * (K + 1) + 1 + j] = (sv[j] - M) - logZ;
  }

  if (mode == 2) {
    for (int j = tid; j < NB; j += NT) {
      float tot = 0.0f;
      for (int s2 = 0; s2 < S; s2++) tot += mass[((size_t)b * S + s2) * NB + j];
      lmass[j] = tot;
    }
    __syncthreads();
    const int CH = NB / NT;
    float cs = 0.0f;
    for (int j = tid * CH; j < (tid + 1) * CH; j++) cs += lmass[j];
    fsum[tid] = cs;
    __syncthreads();
    if (tid == 0) {
      float Z2 = 0.0f;
      for (int c = 0; c < NT; c++) Z2 += fsum[c];
      float W = p * Z2;
      float ca = 0.0f; int c = NT - 1;
      for (; c >= 0; c--) {
        if (ca + fsum[c] >= W) break;
        ca += fsum[c];
      }
      if (c < 0) c = 0;
      int Bb = c * CH, found = -1;
      for (int j = c * CH + CH - 1; j >= c * CH; j--) {
        if (ca + lmass[j] >= W) { found = j; break; }
        ca += lmass[j];
      }
      if (found >= 0) Bb = found;
      rowF[b * 16 + 6] = W; rowF[b * 16 + 7] = ca; rowI[b * 16 + 3] = Bb;
    }
    return;
  }

  int smp; float lx;
  if (mode == 0) {
    smp = gidx; lx = M;
  } else {
    const int keff = min(k, n);
    for (int j = tid; j < keff; j += NT) ev[j] = expf(sv[j] / t - Ms);
    __syncthreads();
    if (tid == 0) {
      float Z = 0.0f;
      for (int j = 0; j < keff; j++) Z += ev[j];
      float W = p * Z;
      float cum = 0.0f; int m = 0;
      for (int j = 0; j < keff; j++) {
        if (cum < W) m++; else break;
        cum += ev[j];
      }
      shI[0] = m;
    }
    __syncthreads();
    const int m = shI[0];
    float key = -FLT_MAX; int kid = 0x7fffffff;
    for (int j = tid; j < m; j += NT) {
      float u = noise[(size_t)b * V + si[j]];
      float g = -logf(-logf(u));
      float kk = sv[j] / t + g;
      if (kk > key || (kk == key && si[j] < kid)) { key = kk; kid = si[j]; }
    }
    for (int off = 32; off; off >>= 1) {
      float ov = __shfl_down(key, off);
      int   oi = __shfl_down(kid, off);
      if (ov > key || (ov == key && oi < kid)) { key = ov; kid = oi; }
    }
    if ((tid & 63) == 0) { wv[tid >> 6] = key; wi[tid >> 6] = kid; }
    __syncthreads();
    if (tid == 0) {
      for (int w2 = 1; w2 < NW; w2++)
        if (wv[w2] > key || (wv[w2] == key && wi[w2] < kid)) { key = wv[w2]; kid = wi[w2]; }
      shI[1] = (kid == 0x7fffffff) ? 0 : kid;
    }
    __syncthreads();
    smp = shI[1];
    if (tid == 0) shF[0] = logits[(size_t)b * V + smp];
    __syncthreads();
    lx = shF[0];
  }
  const float tlp = (lx - M) - logZ;
  int rc = 0;
  for (int j = tid; j < n; j += NT) rc += (((sv[j] - M) - logZ) >= tlp) ? 1 : 0;
  for (int off = 32; off; off >>= 1) rc += __shfl_down(rc, off);
  __syncthreads();
  if ((tid & 63) == 0) wi[tid >> 6] = rc;
  __syncthreads();
  if (tid == 0) {
    int rank = 0;
    for (int w2 = 0; w2 < NW; w2++) rank += wi[w2];
    out[b] = (float)smp;
    out_idx[(size_t)b * (K + 1)] = (float)smp;
    out_lp [(size_t)b * (K + 1)] = tlp;
    out[Bn + 2 * (size_t)Bn * (K + 1) + b] = (float)rank;
  }
}

// ---- K5 (mode2): collect bin-Bb elements + above-bin gumbel partials ------
__global__ __launch_bounds__(NT) void k5(const float* __restrict__ logits,
    const float* __restrict__ noise, int V, int CS,
    const float* __restrict__ rowF, const int* __restrict__ rowI,
    float* __restrict__ l2V, int* __restrict__ l2I, int* __restrict__ cnt2,
    float* __restrict__ gbK, int* __restrict__ gbI)
{
  const int s = blockIdx.x, b = blockIdx.y, tid = threadIdx.x;
  if (rowI[b * 16 + 1] != 2) return;
  const int Bb = rowI[b * 16 + 3];
  const float t = rowF[b * 16 + 4];
  const float* lrow = logits + (size_t)b * V;
  const float* nrow = noise + (size_t)b * V;
  const int lo = s * CS, hi = min(V, lo + CS);
  __shared__ int qn; __shared__ int sbase;
  __shared__ float qv[QCAP]; __shared__ int qi[QCAP];
  __shared__ float wv[NW]; __shared__ int wi[NW];
  if (tid == 0) qn = 0;
  __syncthreads();
  float key = -FLT_MAX; int kid = 0x7fffffff;
  for (int i = lo + tid; i < hi; i += NT) {
    float x = lrow[i];
    int bn = binOf(x);
    if (bn > Bb) {
      float g = -logf(-logf(nrow[i]));
      float kk = x / t + g;
      if (kk > key || (kk == key && i < kid)) { key = kk; kid = i; }
    } else if (bn == Bb) {
      int ppos = atomicAdd(&qn, 1);
      if (ppos < QCAP) { qv[ppos] = x; qi[ppos] = i; }
    }
  }
  for (int off = 32; off; off >>= 1) {
    float ov = __shfl_down(key, off);
    int   oi = __shfl_down(kid, off);
    if (ov > key || (ov == key && oi < kid)) { key = ov; kid = oi; }
  }
  if ((tid & 63) == 0) { wv[tid >> 6] = key; wi[tid >> 6] = kid; }
  __syncthreads();
  if (tid == 0) {
    for (int w = 1; w < NW; w++)
      if (wv[w] > key || (wv[w] == key && wi[w] < kid)) { key = wv[w]; kid = wi[w]; }
    gbK[b * S + s] = key; gbI[b * S + s] = kid;
  }
  int qc = min(qn, QCAP);
  if (tid == 0) sbase = atomicAdd(&cnt2[b], qc);
  __syncthreads();
  for (int j = tid; j < qc; j += NT) {
    int dst = sbase + j;
    if (dst < CAP2) { l2V[b * CAP2 + dst] = qv[j]; l2I[b * CAP2 + dst] = qi[j]; }
  }
}

// ---- K6 (mode2): sort bin, exact prefix, sample, bisect xcrit, finalize ---
__global__ __launch_bounds__(NT) void k6(const float* __restrict__ logits,
    const float* __restrict__ noise, int V, int K,
    const float* __restrict__ l2V, const int* __restrict__ l2I,
    const int* __restrict__ cnt2,
    const float* __restrict__ gbK, const int* __restrict__ gbI,
    float* __restrict__ rowF, const int* __restrict__ rowI,
    float* __restrict__ out, int Bn)
{
  const int b = blockIdx.x, tid = threadIdx.x;
  if (rowI[b * 16 + 1] != 2) return;
  __shared__ float cv[CAP2]; __shared__ int ci2[CAP2];
  __shared__ float sv[CAP2]; __shared__ int si2[CAP2];
  __shared__ float ev[CAP2];
  __shared__ float wv[NW]; __shared__ int wi[NW];
  __shared__ int shI[2];
  const int n2 = min(cnt2[b], CAP2);
  const float M = rowF[b * 16 + 0], logZ = rowF[b * 16 + 1], Ms = rowF[b * 16 + 3];
  const float t = rowF[b * 16 + 4];
  const float W = rowF[b * 16 + 6], CAv = rowF[b * 16 + 7];
  for (int j = tid; j < n2; j += NT) { cv[j] = l2V[b * CAP2 + j]; ci2[j] = l2I[b * CAP2 + j]; }
  __syncthreads();
  for (int c = tid; c < n2; c += NT) {
    float v = cv[c]; int id = ci2[c]; int r = 0;
    for (int j = 0; j < n2; j++) {
      float w = cv[j];
      r += (w > v) || (w == v && ci2[j] < id);
    }
    sv[r] = v; si2[r] = id;
  }
  __syncthreads();
  for (int j = tid; j < n2; j += NT) ev[j] = expf(sv[j] / t - Ms);
  __syncthreads();
  if (tid == 0) {
    float cum = CAv; int last = -1;
    for (int j = 0; j < n2; j++) {
      if (cum < W) last = j; else break;
      cum += ev[j];
    }
    shI[0] = last;
  }
  __syncthreads();
  const int last = shI[0];
  float key = -FLT_MAX; int kid = 0x7fffffff;
  for (int j = tid; j <= last; j += NT) {
    float u = noise[(size_t)b * V + si2[j]];
    float g = -logf(-logf(u));
    float kk = sv[j] / t + g;
    if (kk > key || (kk == key && si2[j] < kid)) { key = kk; kid = si2[j]; }
  }
  for (int off = 32; off; off >>= 1) {
    float ov = __shfl_down(key, off);
    int   oi = __shfl_down(kid, off);
    if (ov > key || (ov == key && oi < kid)) { key = ov; kid = oi; }
  }
  if ((tid & 63) == 0) { wv[tid >> 6] = key; wi[tid >> 6] = kid; }
  __syncthreads();
  if (tid == 0) {
    for (int w = 1; w < NW; w++)
      if (wv[w] > key || (wv[w] == key && wi[w] < kid)) { key = wv[w]; kid = wi[w]; }
    for (int s2 = 0; s2 < S; s2++) {
      float v = gbK[b * S + s2]; int ii = gbI[b * S + s2];
      if (v > key || (v == key && ii < kid)) { key = v; kid = ii; }
    }
    int smp = (kid == 0x7fffffff) ? 0 : kid;
    float lx = logits[(size_t)b * V + smp];
    float tlp = (lx - M) - logZ;
    unsigned loK = f2k(-3.0e38f);
    unsigned hiK = f2k(lx);
    while (hiK - loK > 1u) {
      unsigned mid = loK + ((hiK - loK) >> 1);
      float xm = k2f(mid);
      if (((xm - M) - logZ) >= tlp) hiK = mid; else loK = mid;
    }
    rowF[b * 16 + 9] = k2f(hiK);   // xcrit
    out[b] = (float)smp;
    out[Bn + (size_t)b * (K + 1)] = (float)smp;
    out[Bn + (size_t)Bn * (K + 1) + (size_t)b * (K + 1)] = tlp;
    out[Bn + 2 * (size_t)Bn * (K + 1) + b] = 0.0f;
  }
}

// ---- K7 (mode2): rank = count(x >= xcrit) per slice -> atomic add ---------
__global__ __launch_bounds__(NT) void k7(const float* __restrict__ logits,
    int V, int CS, const float* __restrict__ rowF, const int* __restrict__ rowI,
    float* __restrict__ out, int Bn, int K)
{
  const int s = blockIdx.x, b = blockIdx.y, tid = threadIdx.x;
  if (rowI[b * 16 + 1] != 2) return;
  const float xcrit = rowF[b * 16 + 9];
  const float* lrow = logits + (size_t)b * V;
  const int lo = s * CS, hi = min(V, lo + CS);
  __shared__ int wiv[NW];
  int rc = 0;
  const int vecEnd = lo + ((hi - lo) & ~3);
  const float4* l4 = reinterpret_cast<const float4*>(lrow);
  #pragma unroll 4
  for (int i4 = (lo >> 2) + tid; i4 < (vecEnd >> 2); i4 += NT) {
    float4 x = l4[i4];
    rc += (x.x >= xcrit) + (x.y >= xcrit) + (x.z >= xcrit) + (x.w >= xcrit);
  }
  for (int i = vecEnd + tid; i < hi; i += NT) rc += (lrow[i] >= xcrit);
  for (int off = 32; off; off >>= 1) rc += __shfl_down(rc, off);
  if ((tid & 63) == 0) wiv[tid >> 6] = rc;
  __syncthreads();
  if (tid == 0) {
    int tot = 0;
    for (int w = 0; w < NW; w++) tot += wiv[w];
    atomicAdd(&out[Bn + 2 * (size_t)Bn * (K + 1) + b], (float)tot);
  }
}

extern "C" void kernel_launch(void* const* d_in, const int* in_sizes, int n_in,
                              void* d_out, int out_size, void* d_ws, size_t ws_size,
                              hipStream_t stream) {
  const float* logits = (const float*)d_in[0];
  const float* temp   = (const float*)d_in[1];
  const float* topp   = (const float*)d_in[2];
  const float* noise  = (const float*)d_in[3];
  const int*   topk   = (const int*)d_in[4];
  const int Bn = in_sizes[1];                         // 128
  const int V  = in_sizes[0] / Bn;                    // 128256
  const int K  = (out_size - 2 * Bn) / (2 * Bn) - 1;  // 20
  const int CS = (((V + S - 1) / S) + 3) & ~3;

  char* w = (char*)d_ws;
  int*   hist  = (int*)w;    w += (size_t)Bn * S * NB * 4;
  float* mass  = (float*)w;  w += (size_t)Bn * S * NB * 4;
  int*   cnt1  = (int*)w;    w += (size_t)Bn * 4;
  int*   cnt2  = (int*)w;    w += (size_t)Bn * 4;
  float* sMax  = (float*)w;  w += (size_t)Bn * S * 4;
  int*   sArg  = (int*)w;    w += (size_t)Bn * S * 4;
  float* gbK   = (float*)w;  w += (size_t)Bn * S * 4;
  int*   gbI   = (int*)w;    w += (size_t)Bn * S * 4;
  float* candV = (float*)w;  w += (size_t)Bn * CAP1 * 4;
  int*   candI = (int*)w;    w += (size_t)Bn * CAP1 * 4;
  float* l2V   = (float*)w;  w += (size_t)Bn * CAP2 * 4;
  int*   l2I   = (int*)w;    w += (size_t)Bn * CAP2 * 4;
  float* rowF  = (float*)w;  w += (size_t)Bn * 16 * 4;
  int*   rowI  = (int*)w;    w += (size_t)Bn * 16 * 4;

  dim3 gs(S, Bn);
  k1<<<gs, NT, 0, stream>>>(logits, V, CS, hist, sMax, sArg);
  k2<<<Bn, NT, 0, stream>>>(temp, topp, topk, hist, sMax, sArg, rowF, rowI, cnt1, cnt2);
  k3<<<gs, NT, 0, stream>>>(logits, V, CS, rowF, rowI, mass, candV, candI, cnt1);
  k4<<<Bn, NT, 0, stream>>>(logits, noise, V, K, candV, candI, cnt1, mass, rowF, rowI,
                            (float*)d_out, Bn);
  k5<<<gs, NT, 0, stream>>>(logits, noise, V, CS, rowF, rowI, l2V, l2I, cnt2, gbK, gbI);
  k6<<<Bn, NT, 0, stream>>>(logits, noise, V, K, l2V, l2I, cnt2, gbK, gbI, rowF, rowI,
                            (float*)d_out, Bn);
  k7<<<gs, NT, 0, stream>>>(logits, V, CS, rowF, rowI, (float*)d_out, Bn, K);
}